// Round 9
// baseline (525.210 us; speedup 1.0000x reference)
//
#include <hip/hip_runtime.h>
#include <hip/hip_bf16.h>
#include <stdint.h>

// B=8, N=1024, D=768, H=12, hd=64
// gemm qkv (fp32 in, bf16 out, on-the-fly cvt) -> MFMA flash attention -> gemm proj (bf16 x fp32W)

typedef unsigned short u16;
typedef __attribute__((ext_vector_type(8))) short short8;
typedef __attribute__((ext_vector_type(4))) float f32x4;

#define MFMA16(a, b, c) __builtin_amdgcn_mfma_f32_16x16x32_bf16((a), (b), (c), 0, 0, 0)

static __device__ __forceinline__ u16 f2bf(float f) {
    __hip_bfloat16 h = __float2bfloat16(f);
    return *(u16*)&h;
}
// async global->LDS, 16B per lane; LDS dest must be wave-uniform base + lane*16
static __device__ __forceinline__ void gld16(const void* g, void* l) {
  __builtin_amdgcn_global_load_lds(
      (const __attribute__((address_space(1))) void*)g,
      (__attribute__((address_space(3))) void*)l, 16, 0, 0);
}
// 8 fp32 -> bf16x8 fragment
static __device__ __forceinline__ short8 pack_bf16x8(const float* p) {
  float4 a = *(const float4*)p;
  float4 b = *(const float4*)(p + 4);
  short8 r;
  r[0] = (short)f2bf(a.x); r[1] = (short)f2bf(a.y);
  r[2] = (short)f2bf(a.z); r[3] = (short)f2bf(a.w);
  r[4] = (short)f2bf(b.x); r[5] = (short)f2bf(b.y);
  r[6] = (short)f2bf(b.z); r[7] = (short)f2bf(b.w);
  return r;
}

// ---------------- GEMM1: qkv[8192][2304](bf16) = x[8192][768](f32) * Wqkv[2304][768](f32)^T
// BK=32, 128x128 tile, 4 waves 4x4 of 16x16x32. fp32 staged raw to LDS, cvt at frag read.
__global__ __launch_bounds__(256) void gemm_qkv_f32(
    const float* __restrict__ A,
    const float* __restrict__ B,
    u16* __restrict__ C) {
  __shared__ float As[128 * 32];   // 16 KB
  __shared__ float Bs[128 * 32];   // 16 KB
  const int tid = threadIdx.x;
  const int w = tid >> 6, l = tid & 63;
  const int lane16 = l & 15, quad = l >> 4;
  const int i0 = blockIdx.y * 128, j0 = blockIdx.x * 128;
  const int mh = (w & 1) * 64;
  const int nh = (w >> 1) * 64;

  f32x4 acc[4][4];
  #pragma unroll
  for (int mt = 0; mt < 4; mt++)
    #pragma unroll
    for (int nt = 0; nt < 4; nt++) acc[mt][nt] = (f32x4){0.f, 0.f, 0.f, 0.f};

  for (int kt = 0; kt < 24; kt++) {
    const int k0 = kt * 32;
    __syncthreads();
    #pragma unroll
    for (int s = 0; s < 4; s++) {        // 128x32 fp32 per matrix: 4 gld16/thread
      int idx = tid + s * 256;
      int row = idx >> 3, c4 = (idx & 7) * 4;
      gld16(&A[(size_t)(i0 + row) * 768 + k0 + c4], &As[idx * 4]);
      gld16(&B[(size_t)(j0 + row) * 768 + k0 + c4], &Bs[idx * 4]);
    }
    __syncthreads();

    short8 af[4], bf[4];
    #pragma unroll
    for (int mt = 0; mt < 4; mt++)
      af[mt] = pack_bf16x8(&As[(mh + mt * 16 + lane16) * 32 + quad * 8]);
    #pragma unroll
    for (int nt = 0; nt < 4; nt++)
      bf[nt] = pack_bf16x8(&Bs[(nh + nt * 16 + lane16) * 32 + quad * 8]);
    #pragma unroll
    for (int mt = 0; mt < 4; mt++)
      #pragma unroll
      for (int nt = 0; nt < 4; nt++)
        acc[mt][nt] = MFMA16(af[mt], bf[nt], acc[mt][nt]);
  }

  #pragma unroll
  for (int mt = 0; mt < 4; mt++) {
    #pragma unroll
    for (int nt = 0; nt < 4; nt++) {
      int col = j0 + nh + nt * 16 + lane16;
      #pragma unroll
      for (int r = 0; r < 4; r++) {
        int row = i0 + mh + mt * 16 + quad * 4 + r;
        C[(size_t)row * 2304 + col] = f2bf(acc[mt][nt][r]);
      }
    }
  }
}

// ---------------- GEMM2: out[8192][768](f32) = ctx[8192][768](bf16) * Wproj[768][768](f32)^T + bias
// BK=32, 128x64 tile (grid 12x64 = 768 blocks = 3/CU), 4 waves 4x2 of 16x16x32.
__global__ __launch_bounds__(256) void gemm_proj_mix(
    const u16* __restrict__ A,
    const float* __restrict__ B,
    const float* __restrict__ bias,
    float* __restrict__ Out) {
  __shared__ u16 As[128 * 32];     // 8 KB (bf16)
  __shared__ float Bs[64 * 32];    // 8 KB (fp32)
  const int tid = threadIdx.x;
  const int w = tid >> 6, l = tid & 63;
  const int lane16 = l & 15, quad = l >> 4;
  const int i0 = blockIdx.y * 128, j0 = blockIdx.x * 64;
  const int mh = (w & 1) * 64;
  const int nh = (w >> 1) * 32;

  f32x4 acc[4][2];
  #pragma unroll
  for (int mt = 0; mt < 4; mt++)
    #pragma unroll
    for (int nt = 0; nt < 2; nt++) acc[mt][nt] = (f32x4){0.f, 0.f, 0.f, 0.f};

  for (int kt = 0; kt < 24; kt++) {
    const int k0 = kt * 32;
    __syncthreads();
    #pragma unroll
    for (int s = 0; s < 2; s++) {        // A: 128x32 bf16 -> 2 gld16/thread
      int idx = tid + s * 256;
      int row = idx >> 2, c8 = (idx & 3) * 8;
      gld16(&A[(size_t)(i0 + row) * 768 + k0 + c8], &As[idx * 8]);
    }
    #pragma unroll
    for (int s = 0; s < 2; s++) {        // B: 64x32 fp32 -> 2 gld16/thread
      int idx = tid + s * 256;
      int row = idx >> 3, c4 = (idx & 7) * 4;
      gld16(&B[(size_t)(j0 + row) * 768 + k0 + c4], &Bs[idx * 4]);
    }
    __syncthreads();

    short8 af[4], bf[2];
    #pragma unroll
    for (int mt = 0; mt < 4; mt++)
      af[mt] = *(const short8*)&As[(mh + mt * 16 + lane16) * 32 + quad * 8];
    #pragma unroll
    for (int nt = 0; nt < 2; nt++)
      bf[nt] = pack_bf16x8(&Bs[(nh + nt * 16 + lane16) * 32 + quad * 8]);
    #pragma unroll
    for (int mt = 0; mt < 4; mt++)
      #pragma unroll
      for (int nt = 0; nt < 2; nt++)
        acc[mt][nt] = MFMA16(af[mt], bf[nt], acc[mt][nt]);
  }

  #pragma unroll
  for (int mt = 0; mt < 4; mt++) {
    #pragma unroll
    for (int nt = 0; nt < 2; nt++) {
      int col = j0 + nh + nt * 16 + lane16;
      float bv = bias[col];
      #pragma unroll
      for (int r = 0; r < 4; r++) {
        int row = i0 + mh + mt * 16 + quad * 4 + r;
        Out[(size_t)row * 768 + col] = acc[mt][nt][r] + bv;
      }
    }
  }
}

// ---------------- Attention: MFMA flash, transposed-S, fixed-max softmax.
// (r6 version — best known: 55.6 us.) Single K/V LDS buffer, 2 barriers/chunk.
// XCD swizzle: idx = rb*96 + bh so all 8 row-blocks of one (b,h) share an XCD L2.
// Block = 4 waves, 128 q-rows, grid 768.
__global__ __launch_bounds__(256, 4) void attn_mfma(
    const u16* __restrict__ qkv,   // bf16 bits, [B*N][2304]; q +0, k +768, v +1536 (+h*64)
    const int* __restrict__ mask,
    u16* __restrict__ ctx) {
  __shared__ u16 Ks[64][72];      // [key][dim]
  __shared__ u16 Vt[64][72];      // [dim][key]
  __shared__ u16 Ps[4][32][72];   // per-wave P [qrow_local][key]
  __shared__ float mkb[64];       // 0 or -1e38 additive key-mask bias
  __shared__ int mqs[128];

  const int tid = threadIdx.x;
  const int w = tid >> 6, l = tid & 63;
  const int lane16 = l & 15, quad = l >> 4;
  const int idx = blockIdx.x;
  const int bh = idx % 96;        // 96 % 8 == 0 -> same bh => same XCD
  const int rb = idx / 96;
  const int b = bh / 12, h = bh % 12;
  const int n0 = rb * 128;
  const int baseRow = b * 1024;

  // staging thread mapping
  const int key_s = tid >> 2, ds_s = (tid & 3) * 16;      // K: 1 key, 32 dims
  const int kA_s = (tid & 31) * 2, dg_s = tid >> 5;       // V: 2 keys, 8 dims

  if (tid < 128) mqs[tid] = mask[baseRow + n0 + tid];

  // Q fragments (used as MFMA B operand): n=lane16 (local qrow), k=quad*8+j
  short8 qfrag[2][2];
  #pragma unroll
  for (int qt = 0; qt < 2; qt++) {
    const u16* qp = qkv + (size_t)(baseRow + n0 + w*32 + qt*16 + lane16) * 2304 + h*64;
    #pragma unroll
    for (int ks = 0; ks < 2; ks++)
      qfrag[qt][ks] = *(const short8*)(qp + ks*32 + quad*8);
  }

  f32x4 oacc[2][4];     // [qt][nt(dim)]; C-layout row=quad*4+r=qrow, col=lane16=dim
  #pragma unroll
  for (int qt = 0; qt < 2; qt++)
    #pragma unroll
    for (int nt = 0; nt < 4; nt++) oacc[qt][nt] = (f32x4){0.f, 0.f, 0.f, 0.f};
  float lsum[2] = {0.f, 0.f};   // per-lane partial over this lane's keys

  // exp(s/8 - 16) == exp2(s*K1 + K0); fixed max >> max score (~8 sigma), overflow-free.
  const float K1 = 0.18033688011112043f;   // log2(e)/8
  const float K0 = -23.083120654223415f;   // -16*log2(e)

  for (int c = 0; c < 16; c++) {
    if (c) __syncthreads();   // prior chunk's LDS reads complete before overwrite
    {
      const u16* kp = qkv + (size_t)(baseRow + c*64 + key_s) * 2304 + 768 + h*64 + ds_s;
      uint4 kr0 = *(const uint4*)kp;
      uint4 kr1 = *(const uint4*)(kp + 8);
      const u16* vp = qkv + (size_t)(baseRow + c*64 + kA_s) * 2304 + 1536 + h*64 + dg_s*8;
      uint4 vr0 = *(const uint4*)vp;
      uint4 vr1 = *(const uint4*)(vp + 2304);
      *(uint4*)&Ks[key_s][ds_s]     = kr0;
      *(uint4*)&Ks[key_s][ds_s + 8] = kr1;
      const u16* va = (const u16*)&vr0;
      const u16* vb = (const u16*)&vr1;
      #pragma unroll
      for (int j = 0; j < 8; j++)
        *(unsigned int*)&Vt[dg_s*8 + j][kA_s] =
            (unsigned int)va[j] | ((unsigned int)vb[j] << 16);
      if (tid < 64) mkb[tid] = mask[baseRow + c*64 + tid] ? 0.f : -1e38f;
    }
    __syncthreads();

    // S^T = K * Q^T : A=K (m=key), B=Q (n=qrow). C-layout: row=key, col=qrow.
    f32x4 sacc[4][2];
    #pragma unroll
    for (int kt = 0; kt < 4; kt++)
      #pragma unroll
      for (int qt = 0; qt < 2; qt++) sacc[kt][qt] = (f32x4){0.f, 0.f, 0.f, 0.f};
    #pragma unroll
    for (int ks = 0; ks < 2; ks++) {
      short8 kf[4];
      #pragma unroll
      for (int kt = 0; kt < 4; kt++)
        kf[kt] = *(const short8*)&Ks[kt*16 + lane16][ks*32 + quad*8];
      #pragma unroll
      for (int kt = 0; kt < 4; kt++)
        #pragma unroll
        for (int qt = 0; qt < 2; qt++)
          sacc[kt][qt] = MFMA16(kf[kt], qfrag[qt][ks], sacc[kt][qt]);
    }

    // softmax: row=quad*4+r = key-local, col=lane16 = qrow-local. Vectorized P write.
    #pragma unroll
    for (int kt = 0; kt < 4; kt++) {
      #pragma unroll
      for (int qt = 0; qt < 2; qt++) {
        u16 pk[4];
        #pragma unroll
        for (int r = 0; r < 4; r++) {
          int keyl = kt*16 + quad*4 + r;
          float e = __builtin_amdgcn_exp2f(fmaf(sacc[kt][qt][r], K1, K0) + mkb[keyl]);
          lsum[qt] += e;
          pk[r] = f2bf(e);
        }
        uint2 pv;
        pv.x = (unsigned int)pk[0] | ((unsigned int)pk[1] << 16);
        pv.y = (unsigned int)pk[2] | ((unsigned int)pk[3] << 16);
        *(uint2*)&Ps[w][qt*16 + lane16][kt*16 + quad*4] = pv;
      }
    }

    // O += P * V : A=P (m=qrow, k=key) own-wave LDS; B=V^T (n=dim, k=key) from Vt.
    #pragma unroll
    for (int kc = 0; kc < 2; kc++) {
      short8 pf[2], vf[4];
      #pragma unroll
      for (int qt = 0; qt < 2; qt++)
        pf[qt] = *(const short8*)&Ps[w][qt*16 + lane16][kc*32 + quad*8];
      #pragma unroll
      for (int nt = 0; nt < 4; nt++)
        vf[nt] = *(const short8*)&Vt[nt*16 + lane16][kc*32 + quad*8];
      #pragma unroll
      for (int qt = 0; qt < 2; qt++)
        #pragma unroll
        for (int nt = 0; nt < 4; nt++)
          oacc[qt][nt] = MFMA16(pf[qt], vf[nt], oacc[qt][nt]);
    }
  }

  // lsum: reduce across quads, then redistribute to the C-layout row owner.
  float linv[2][4];
  #pragma unroll
  for (int qt = 0; qt < 2; qt++) {
    float s = lsum[qt];
    s += __shfl_xor(s, 16);
    s += __shfl_xor(s, 32);   // every lane: total for qrow = its lane16 (tile qt)
    #pragma unroll
    for (int r = 0; r < 4; r++)
      linv[qt][r] = 1.0f / __shfl(s, quad*4 + r);
  }
  // store; masked query rows get exactly their own V row (bit-exact copy)
  #pragma unroll
  for (int qt = 0; qt < 2; qt++) {
    #pragma unroll
    for (int r = 0; r < 4; r++) {
      int rl = w*32 + qt*16 + quad*4 + r;
      int rg = n0 + rl;
      int mq = mqs[rl];
      #pragma unroll
      for (int nt = 0; nt < 4; nt++) {
        u16 outv;
        if (mq) {
          outv = f2bf(oacc[qt][nt][r] * linv[qt][r]);
        } else {
          outv = qkv[(size_t)(baseRow + rg) * 2304 + 1536 + h*64 + nt*16 + lane16];
        }
        ctx[(size_t)(baseRow + rg) * 768 + h*64 + nt*16 + lane16] = outv;
      }
    }
  }
}

extern "C" void kernel_launch(void* const* d_in, const int* in_sizes, int n_in,
                              void* d_out, int out_size, void* d_ws, size_t ws_size,
                              hipStream_t stream) {
  const float* x     = (const float*)d_in[0];
  const int*   mask  = (const int*)d_in[1];
  const float* Wqkv  = (const float*)d_in[2];
  const float* Wproj = (const float*)d_in[3];
  const float* bproj = (const float*)d_in[4];
  float* out = (float*)d_out;

  char* wsb = (char*)d_ws;
  u16* qkv = (u16*)wsb;                                 // 8192*2304 bf16 = 37.75 MB
  u16* ctx = (u16*)(wsb + (size_t)8192 * 2304 * 2);     // 8192*768 bf16 = 12.58 MB

  gemm_qkv_f32<<<dim3(18, 64), 256, 0, stream>>>(x, Wqkv, qkv);
  attn_mfma<<<dim3(768), 256, 0, stream>>>(qkv, mask, ctx);
  gemm_proj_mix<<<dim3(12, 64), 256, 0, stream>>>(ctx, Wproj, bproj, out);
}

// Round 10
// 201.222 us; speedup vs baseline: 2.6101x; 2.6101x over previous
//
#include <hip/hip_runtime.h>
#include <hip/hip_bf16.h>
#include <stdint.h>

// B=8, N=1024, D=768, H=12, hd=64
// cvt(x,Wqkv,Wproj -> bf16 ws) -> MFMA gemm qkv -> MFMA flash attention -> MFMA gemm proj + bias

typedef unsigned short u16;
typedef __attribute__((ext_vector_type(8))) short short8;
typedef __attribute__((ext_vector_type(4))) float f32x4;

#define MFMA16(a, b, c) __builtin_amdgcn_mfma_f32_16x16x32_bf16((a), (b), (c), 0, 0, 0)

static __device__ __forceinline__ u16 f2bf(float f) {
    __hip_bfloat16 h = __float2bfloat16(f);
    return *(u16*)&h;
}
// async global->LDS, 16B per lane; LDS dest must be wave-uniform base + lane*16
static __device__ __forceinline__ void gld16(const u16* g, u16* l) {
  __builtin_amdgcn_global_load_lds(
      (const __attribute__((address_space(1))) void*)g,
      (__attribute__((address_space(3))) void*)l, 16, 0, 0);
}

// ---------------- fp32 -> bf16 conversion of the three input tensors
__global__ __launch_bounds__(256) void cvt_bf16(
    const float* __restrict__ s0, u16* __restrict__ d0, int n0,
    const float* __restrict__ s1, u16* __restrict__ d1, int n1,
    const float* __restrict__ s2, u16* __restrict__ d2, int n2) {
  int i = (blockIdx.x * 256 + threadIdx.x) * 4;
  const float* s; u16* d;
  if (i < n0) { s = s0 + i; d = d0 + i; }
  else if ((i -= n0) < n1) { s = s1 + i; d = d1 + i; }
  else if ((i -= n1) < n2) { s = s2 + i; d = d2 + i; }
  else return;
  float4 v = *(const float4*)s;
  ushort4 o;
  o.x = f2bf(v.x); o.y = f2bf(v.y); o.z = f2bf(v.z); o.w = f2bf(v.w);
  *(ushort4*)d = o;
}

// ---------------- MFMA GEMM: C[M][LDC] = A[M][K](bf16) * B[N][K](bf16)^T
// m97 structure: BK=32, BM=128, BN in {128,64}; 4 waves, each 64 x BN/2.
template<int K, int BN, int LDC, bool BF16OUT>
__global__ __launch_bounds__(256) void gemm_bt(
    const u16* __restrict__ A,
    const u16* __restrict__ B,
    void* __restrict__ Cout,
    const float* __restrict__ bias) {
  constexpr int NT = BN / 32;          // n-tiles per wave
  __shared__ u16 As[128 * 32];
  __shared__ u16 Bs[BN * 32];
  const int tid = threadIdx.x;
  const int w = tid >> 6, l = tid & 63;
  const int lane16 = l & 15, quad = l >> 4;
  const int i0 = blockIdx.y * 128, j0 = blockIdx.x * BN;
  const int mh = (w & 1) * 64;
  const int nh = (w >> 1) * (BN / 2);

  f32x4 acc[4][NT];
  #pragma unroll
  for (int mt = 0; mt < 4; mt++)
    #pragma unroll
    for (int nt = 0; nt < NT; nt++) acc[mt][nt] = (f32x4){0.f, 0.f, 0.f, 0.f};

  for (int kt = 0; kt < K / 32; kt++) {
    const int k0 = kt * 32;
    __syncthreads();
    #pragma unroll
    for (int s = 0; s < 2; s++) {            // A: 128x32 bf16 -> 2 gld16/thread
      int idx = tid + s * 256;
      int row = idx >> 2, c8 = (idx & 3) * 8;
      gld16(&A[(size_t)(i0 + row) * K + k0 + c8], &As[idx * 8]);
    }
    #pragma unroll
    for (int s = 0; s < BN / 64; s++) {      // B: BNx32 bf16
      int idx = tid + s * 256;
      int row = idx >> 2, c8 = (idx & 3) * 8;
      gld16(&B[(size_t)(j0 + row) * K + k0 + c8], &Bs[idx * 8]);
    }
    __syncthreads();

    short8 af[4], bf[NT];
    #pragma unroll
    for (int mt = 0; mt < 4; mt++)
      af[mt] = *(const short8*)&As[(mh + mt * 16 + lane16) * 32 + quad * 8];
    #pragma unroll
    for (int nt = 0; nt < NT; nt++)
      bf[nt] = *(const short8*)&Bs[(nh + nt * 16 + lane16) * 32 + quad * 8];
    #pragma unroll
    for (int mt = 0; mt < 4; mt++)
      #pragma unroll
      for (int nt = 0; nt < NT; nt++)
        acc[mt][nt] = MFMA16(af[mt], bf[nt], acc[mt][nt]);
  }

  #pragma unroll
  for (int mt = 0; mt < 4; mt++) {
    #pragma unroll
    for (int nt = 0; nt < NT; nt++) {
      int col = j0 + nh + nt * 16 + lane16;
      #pragma unroll
      for (int r = 0; r < 4; r++) {
        int row = i0 + mh + mt * 16 + quad * 4 + r;
        if (BF16OUT) {
          ((u16*)Cout)[(size_t)row * LDC + col] = f2bf(acc[mt][nt][r]);
        } else {
          ((float*)Cout)[(size_t)row * LDC + col] = acc[mt][nt][r] + bias[col];
        }
      }
    }
  }
}

// ---------------- Attention: MFMA flash, transposed-S, fixed-max softmax.
// (r6 version — best known: 55.6 us.) Single K/V LDS buffer, 2 barriers/chunk.
// XCD swizzle: idx = rb*96 + bh so all 8 row-blocks of one (b,h) share an XCD L2.
// Block = 4 waves, 128 q-rows, grid 768.
__global__ __launch_bounds__(256, 4) void attn_mfma(
    const u16* __restrict__ qkv,   // bf16 bits, [B*N][2304]; q +0, k +768, v +1536 (+h*64)
    const int* __restrict__ mask,
    u16* __restrict__ ctx) {
  __shared__ u16 Ks[64][72];      // [key][dim]
  __shared__ u16 Vt[64][72];      // [dim][key]
  __shared__ u16 Ps[4][32][72];   // per-wave P [qrow_local][key]
  __shared__ float mkb[64];       // 0 or -1e38 additive key-mask bias
  __shared__ int mqs[128];

  const int tid = threadIdx.x;
  const int w = tid >> 6, l = tid & 63;
  const int lane16 = l & 15, quad = l >> 4;
  const int idx = blockIdx.x;
  const int bh = idx % 96;        // 96 % 8 == 0 -> same bh => same XCD
  const int rb = idx / 96;
  const int b = bh / 12, h = bh % 12;
  const int n0 = rb * 128;
  const int baseRow = b * 1024;

  // staging thread mapping
  const int key_s = tid >> 2, ds_s = (tid & 3) * 16;      // K: 1 key, 32 dims
  const int kA_s = (tid & 31) * 2, dg_s = tid >> 5;       // V: 2 keys, 8 dims

  if (tid < 128) mqs[tid] = mask[baseRow + n0 + tid];

  // Q fragments (used as MFMA B operand): n=lane16 (local qrow), k=quad*8+j
  short8 qfrag[2][2];
  #pragma unroll
  for (int qt = 0; qt < 2; qt++) {
    const u16* qp = qkv + (size_t)(baseRow + n0 + w*32 + qt*16 + lane16) * 2304 + h*64;
    #pragma unroll
    for (int ks = 0; ks < 2; ks++)
      qfrag[qt][ks] = *(const short8*)(qp + ks*32 + quad*8);
  }

  f32x4 oacc[2][4];     // [qt][nt(dim)]; C-layout row=quad*4+r=qrow, col=lane16=dim
  #pragma unroll
  for (int qt = 0; qt < 2; qt++)
    #pragma unroll
    for (int nt = 0; nt < 4; nt++) oacc[qt][nt] = (f32x4){0.f, 0.f, 0.f, 0.f};
  float lsum[2] = {0.f, 0.f};   // per-lane partial over this lane's keys

  // exp(s/8 - 16) == exp2(s*K1 + K0); fixed max >> max score (~8 sigma), overflow-free.
  const float K1 = 0.18033688011112043f;   // log2(e)/8
  const float K0 = -23.083120654223415f;   // -16*log2(e)

  for (int c = 0; c < 16; c++) {
    if (c) __syncthreads();   // prior chunk's LDS reads complete before overwrite
    {
      const u16* kp = qkv + (size_t)(baseRow + c*64 + key_s) * 2304 + 768 + h*64 + ds_s;
      uint4 kr0 = *(const uint4*)kp;
      uint4 kr1 = *(const uint4*)(kp + 8);
      const u16* vp = qkv + (size_t)(baseRow + c*64 + kA_s) * 2304 + 1536 + h*64 + dg_s*8;
      uint4 vr0 = *(const uint4*)vp;
      uint4 vr1 = *(const uint4*)(vp + 2304);
      *(uint4*)&Ks[key_s][ds_s]     = kr0;
      *(uint4*)&Ks[key_s][ds_s + 8] = kr1;
      const u16* va = (const u16*)&vr0;
      const u16* vb = (const u16*)&vr1;
      #pragma unroll
      for (int j = 0; j < 8; j++)
        *(unsigned int*)&Vt[dg_s*8 + j][kA_s] =
            (unsigned int)va[j] | ((unsigned int)vb[j] << 16);
      if (tid < 64) mkb[tid] = mask[baseRow + c*64 + tid] ? 0.f : -1e38f;
    }
    __syncthreads();

    // S^T = K * Q^T : A=K (m=key), B=Q (n=qrow). C-layout: row=key, col=qrow.
    f32x4 sacc[4][2];
    #pragma unroll
    for (int kt = 0; kt < 4; kt++)
      #pragma unroll
      for (int qt = 0; qt < 2; qt++) sacc[kt][qt] = (f32x4){0.f, 0.f, 0.f, 0.f};
    #pragma unroll
    for (int ks = 0; ks < 2; ks++) {
      short8 kf[4];
      #pragma unroll
      for (int kt = 0; kt < 4; kt++)
        kf[kt] = *(const short8*)&Ks[kt*16 + lane16][ks*32 + quad*8];
      #pragma unroll
      for (int kt = 0; kt < 4; kt++)
        #pragma unroll
        for (int qt = 0; qt < 2; qt++)
          sacc[kt][qt] = MFMA16(kf[kt], qfrag[qt][ks], sacc[kt][qt]);
    }

    // softmax: row=quad*4+r = key-local, col=lane16 = qrow-local. Vectorized P write.
    #pragma unroll
    for (int kt = 0; kt < 4; kt++) {
      #pragma unroll
      for (int qt = 0; qt < 2; qt++) {
        u16 pk[4];
        #pragma unroll
        for (int r = 0; r < 4; r++) {
          int keyl = kt*16 + quad*4 + r;
          float e = __builtin_amdgcn_exp2f(fmaf(sacc[kt][qt][r], K1, K0) + mkb[keyl]);
          lsum[qt] += e;
          pk[r] = f2bf(e);
        }
        uint2 pv;
        pv.x = (unsigned int)pk[0] | ((unsigned int)pk[1] << 16);
        pv.y = (unsigned int)pk[2] | ((unsigned int)pk[3] << 16);
        *(uint2*)&Ps[w][qt*16 + lane16][kt*16 + quad*4] = pv;
      }
    }

    // O += P * V : A=P (m=qrow, k=key) own-wave LDS; B=V^T (n=dim, k=key) from Vt.
    #pragma unroll
    for (int kc = 0; kc < 2; kc++) {
      short8 pf[2], vf[4];
      #pragma unroll
      for (int qt = 0; qt < 2; qt++)
        pf[qt] = *(const short8*)&Ps[w][qt*16 + lane16][kc*32 + quad*8];
      #pragma unroll
      for (int nt = 0; nt < 4; nt++)
        vf[nt] = *(const short8*)&Vt[nt*16 + lane16][kc*32 + quad*8];
      #pragma unroll
      for (int qt = 0; qt < 2; qt++)
        #pragma unroll
        for (int nt = 0; nt < 4; nt++)
          oacc[qt][nt] = MFMA16(pf[qt], vf[nt], oacc[qt][nt]);
    }
  }

  // lsum: reduce across quads, then redistribute to the C-layout row owner.
  float linv[2][4];
  #pragma unroll
  for (int qt = 0; qt < 2; qt++) {
    float s = lsum[qt];
    s += __shfl_xor(s, 16);
    s += __shfl_xor(s, 32);   // every lane: total for qrow = its lane16 (tile qt)
    #pragma unroll
    for (int r = 0; r < 4; r++)
      linv[qt][r] = 1.0f / __shfl(s, quad*4 + r);
  }
  // store; masked query rows get exactly their own V row (bit-exact copy)
  #pragma unroll
  for (int qt = 0; qt < 2; qt++) {
    #pragma unroll
    for (int r = 0; r < 4; r++) {
      int rl = w*32 + qt*16 + quad*4 + r;
      int rg = n0 + rl;
      int mq = mqs[rl];
      #pragma unroll
      for (int nt = 0; nt < 4; nt++) {
        u16 outv;
        if (mq) {
          outv = f2bf(oacc[qt][nt][r] * linv[qt][r]);
        } else {
          outv = qkv[(size_t)(baseRow + rg) * 2304 + 1536 + h*64 + nt*16 + lane16];
        }
        ctx[(size_t)(baseRow + rg) * 768 + h*64 + nt*16 + lane16] = outv;
      }
    }
  }
}

extern "C" void kernel_launch(void* const* d_in, const int* in_sizes, int n_in,
                              void* d_out, int out_size, void* d_ws, size_t ws_size,
                              hipStream_t stream) {
  const float* x     = (const float*)d_in[0];
  const int*   mask  = (const int*)d_in[1];
  const float* Wqkv  = (const float*)d_in[2];
  const float* Wproj = (const float*)d_in[3];
  const float* bproj = (const float*)d_in[4];
  float* out = (float*)d_out;

  const int NX = 8192 * 768;
  const int NQ = 2304 * 768;
  const int NP = 768 * 768;

  char* wsb = (char*)d_ws;
  u16* qkv    = (u16*)wsb;                                  // 37.75 MB
  u16* ctx    = (u16*)(wsb + (size_t)8192 * 2304 * 2);      // 12.58 MB
  u16* xb     = (u16*)(wsb + (size_t)8192 * 2304 * 2 + (size_t)8192 * 768 * 2);
  u16* wqkvb  = xb + NX;
  u16* wprojb = wqkvb + NQ;

  int cvt_blocks = ((NX + NQ + NP) / 4 + 255) / 256;
  cvt_bf16<<<dim3(cvt_blocks), 256, 0, stream>>>(x, xb, NX, Wqkv, wqkvb, NQ, Wproj, wprojb, NP);

  gemm_bt<768, 128, 2304, true><<<dim3(18, 64), 256, 0, stream>>>(xb, wqkvb, qkv, nullptr);
  attn_mfma<<<dim3(768), 256, 0, stream>>>(qkv, mask, ctx);
  gemm_bt<768, 64, 768, false><<<dim3(12, 64), 256, 0, stream>>>(ctx, wprojb, out, bproj);
}